// Round 11
// baseline (295.280 us; speedup 1.0000x reference)
//
#include <hip/hip_runtime.h>

// GCN: agg-before-GEMM on both layers (A(hW) = (Ah)W).
//   es  = bf16( dinv[i] * emb[x[i]] )               (N x 32, 3.2 MB, L2-resident)
//   L1 fused: a1(LDS) = dinv*(es[i]+sum es[src]);  hs = bf16(dinv*relu(a1@W1+b1))
//   L2 fused: a2(LDS) = dinv*(hs[i]+sum hs[src]);  out = a2@W2 + b2
// CSR build: bucket -> chunked-LDS-histogram counting sort (no global atomics).
// R11: staged edges packed to one int ((dlocal<<17)|src) halving staging traffic;
// k_l1 gather 8 lanes x ushort4 (was 32 x 2B scalar); k_l2 gather 16 lanes x 16B.

#define NPP   6250     // nodes per partition (N=50000 / 8)
#define NC    32       // chunks per partition

static inline int cdiv(int a, int b){ return (a + b - 1) / b; }

__device__ __forceinline__ unsigned short f2bf(float f){
    unsigned int u = __float_as_uint(f);
    u += 0x7fffu + ((u >> 16) & 1u);          // round-to-nearest-even
    return (unsigned short)(u >> 16);
}
__device__ __forceinline__ float bf2f(unsigned short b){
    return __uint_as_float(((unsigned int)b) << 16);
}
__device__ __forceinline__ float bflo(unsigned int u){ return __uint_as_float(u << 16); }
__device__ __forceinline__ float bfhi(unsigned int u){ return __uint_as_float(u & 0xffff0000u); }

__global__ void k_zero_i32(int* __restrict__ p, int n){
    int i = blockIdx.x * blockDim.x + threadIdx.x;
    if (i < n) p[i] = 0;
}

// Bucket edges by dst-range into 8 staged partition arrays, packed
// (dlocal<<17)|src. LDS tiles, per-block coalesced flush (~2k gcur atomics total).
__global__ __launch_bounds__(256) void k_bucket(const int* __restrict__ src,
        const int* __restrict__ dst, int E, int* __restrict__ staged,
        int* __restrict__ gcur, int npp, int C){
    __shared__ int qcnt[8];
    __shared__ int qbase[8];
    __shared__ int qbuf[8 * 256];   // 8 KB
    int tid = threadIdx.x;
    if (tid < 8) qcnt[tid] = 0;
    __syncthreads();
    int e0 = blockIdx.x * 1024 + tid * 4;
    if (e0 + 3 < E){
        int4 d4 = *(const int4*)(dst + e0);
        int4 s4 = *(const int4*)(src + e0);
        int dd[4] = {d4.x, d4.y, d4.z, d4.w};
        int ss[4] = {s4.x, s4.y, s4.z, s4.w};
        #pragma unroll
        for (int i = 0; i < 4; i++){
            int p = dd[i] / npp;
            int pk = ((dd[i] - p * npp) << 17) | ss[i];
            int pos = atomicAdd(&qcnt[p], 1);
            if (pos < 256) qbuf[p * 256 + pos] = pk;
            else {          // statistically unreachable overflow fallback
                int gp = atomicAdd(&gcur[p], 1);
                staged[(size_t)p * C + gp] = pk;
            }
        }
    } else {
        for (int e = e0; e < E && e < e0 + 4; e++){
            int d = dst[e], s = src[e];
            int p = d / npp;
            int pk = ((d - p * npp) << 17) | s;
            int pos = atomicAdd(&qcnt[p], 1);
            if (pos < 256) qbuf[p * 256 + pos] = pk;
            else {
                int gp = atomicAdd(&gcur[p], 1);
                staged[(size_t)p * C + gp] = pk;
            }
        }
    }
    __syncthreads();
    if (tid < 8){
        int nq = min(qcnt[tid], 256);
        qbase[tid] = (nq > 0) ? atomicAdd(&gcur[tid], nq) : 0;
    }
    __syncthreads();
    for (int b = 0; b < 8; b++){
        int nq = min(qcnt[b], 256);
        int gb = qbase[b];
        for (int i = tid; i < nq; i += 256)
            staged[(size_t)b * C + gb + i] = qbuf[b * 256 + i];
    }
}

// Per-(partition,chunk) dst histogram via LDS atomics -> H[p][c][0..npp).
__global__ __launch_bounds__(256) void k_hist(const int* __restrict__ staged,
        const int* __restrict__ gcur, int C, int CH, int npp, int* __restrict__ H){
    __shared__ int hist[NPP];
    int part  = blockIdx.x & 7;
    int chunk = blockIdx.x >> 3;
    int tid = threadIdx.x;
    for (int i = tid; i < npp; i += 256) hist[i] = 0;
    __syncthreads();
    int pc = gcur[part];
    int e0 = chunk * CH, e1 = min(e0 + CH, pc);
    const int* sd = staged + (size_t)part * C;
    for (int e = e0 + tid; e < e1; e += 256)
        atomicAdd(&hist[(unsigned)sd[e] >> 17], 1);
    __syncthreads();
    int* Hrow = H + (size_t)(part * NC + chunk) * npp;
    for (int i = tid; i < npp; i += 256) Hrow[i] = hist[i];
}

// Per-node serial prefix over the NC chunk histograms: H becomes per-chunk
// exclusive base rank; ecount = total; dinv fused; per-block sums -> bsum.
__global__ __launch_bounds__(256) void k_nodescan(int* __restrict__ H, int npp, int n,
        int* __restrict__ ecount, float* __restrict__ dinv, int* __restrict__ bsum){
    __shared__ int s[256];
    int t = blockIdx.x * 256 + threadIdx.x;   // t == node id (partitions contiguous)
    int run = 0;
    if (t < 8 * npp && t < n){
        int p  = t / npp;
        int dl = t - p * npp;
        #pragma unroll
        for (int c = 0; c < NC; c++){
            size_t idx = (size_t)(p * NC + c) * npp + dl;
            int v = H[idx];
            H[idx] = run;
            run += v;
        }
        ecount[t] = run;
        dinv[t] = rsqrtf((float)run + 1.0f);   // +1 self-loop
    }
    s[threadIdx.x] = run;
    __syncthreads();
    for (int d = 128; d > 0; d >>= 1){
        if (threadIdx.x < d) s[threadIdx.x] += s[threadIdx.x + d];
        __syncthreads();
    }
    if (threadIdx.x == 0) bsum[blockIdx.x] = s[0];
}

// Fused scanB+scanC: every block re-scans the nb block sums in LDS (nb<=256),
// then does its 256-element Hillis-Steele scan -> offsets.
__global__ __launch_bounds__(256) void k_scanBC(const int* __restrict__ ecount, int n,
        const int* __restrict__ bsum, int nb, int* __restrict__ offsets){
    __shared__ int bs[256];
    __shared__ int s[256];
    int t = threadIdx.x;
    bs[t] = (t < nb) ? bsum[t] : 0;
    __syncthreads();
    if (t == 0){
        int run = 0;
        for (int b = 0; b < nb; b++){ int v = bs[b]; bs[b] = run; run += v; }
    }
    __syncthreads();
    int i = blockIdx.x * 256 + t;
    int v = (i < n) ? ecount[i] : 0;
    s[t] = v;
    __syncthreads();
    for (int d = 1; d < 256; d <<= 1){
        int x = (t >= d) ? s[t - d] : 0;
        __syncthreads();
        s[t] += x;
        __syncthreads();
    }
    if (i < n) offsets[i] = bs[blockIdx.x] + s[t] - v;
}

// Fill csr via LDS cursor preloaded with chunk base ranks. No global atomics.
__global__ __launch_bounds__(256) void k_fill3(const int* __restrict__ staged,
        const int* __restrict__ gcur, int C, int CH, int npp,
        const int* __restrict__ H, const int* __restrict__ offsets,
        int* __restrict__ csr_src){
    __shared__ int cur[NPP];
    int part  = blockIdx.x & 7;
    int chunk = blockIdx.x >> 3;
    int tid = threadIdx.x;
    const int* Hrow = H + (size_t)(part * NC + chunk) * npp;
    for (int i = tid; i < npp; i += 256) cur[i] = Hrow[i];
    __syncthreads();
    int pc = gcur[part];
    int lo = part * npp;
    int e0 = chunk * CH, e1 = min(e0 + CH, pc);
    const int* sd = staged + (size_t)part * C;
    for (int e = e0 + tid; e < e1; e += 256){
        int pk = sd[e];
        int dl = (unsigned)pk >> 17;
        int r = atomicAdd(&cur[dl], 1);
        csr_src[offsets[lo + dl] + r] = pk & 0x1FFFF;
    }
}

// es[i][c] = bf16( emb[x[i]][c] * dinv[i] )
__global__ void k_scale(const float* __restrict__ emb, const int* __restrict__ x,
                        const float* __restrict__ dinv, unsigned short* __restrict__ es, int n){
    int idx = blockIdx.x * blockDim.x + threadIdx.x;
    if (idx >= n * 32) return;
    int i = idx >> 5;
    int c = idx & 31;
    es[idx] = f2bf(emb[(size_t)x[i] * 32 + c] * dinv[i]);
}

// Layer 1 fused: gather(32-dim es) -> LDS a1 tile -> GEMM W1 -> hs.
// 32 nodes/block; phase A: 8 lanes/node x ushort4 (8 B), unroll 8;
// phase B: thread = 4 nodes x 4 cols against W1 in LDS.
__global__ __launch_bounds__(256) void k_l1(const unsigned short* __restrict__ es,
        const int* __restrict__ offsets, const int* __restrict__ ecount,
        const int* __restrict__ csr, const float* __restrict__ dinv,
        const float* __restrict__ W1, const float* __restrict__ b1,
        unsigned short* __restrict__ hs, int n){
    __shared__ float w[32 * 128];     // 16 KB
    __shared__ float a1t[32 * 32];    // 4 KB
    for (int i = threadIdx.x; i < 32 * 128; i += 256) w[i] = W1[i];
    int g    = threadIdx.x >> 3;      // 32 groups
    int lane = threadIdx.x & 7;       // 8 lanes/node
    int node = blockIdx.x * 32 + g;
    // --- phase A: aggregate into LDS ---
    if (node < n){
        int off = offsets[node], cnt = ecount[node];
        int c4 = lane * 4;
        ushort4 sv = *(const ushort4*)(es + (size_t)node * 32 + c4);  // self-loop
        float s0 = bf2f(sv.x), s1 = bf2f(sv.y), s2 = bf2f(sv.z), s3 = bf2f(sv.w);
        float t0 = 0.f, t1 = 0.f, t2 = 0.f, t3 = 0.f;
        int e = 0;
        for (; e + 8 <= cnt; e += 8){
            int i0 = csr[off + e + 0], i1 = csr[off + e + 1];
            int i2 = csr[off + e + 2], i3 = csr[off + e + 3];
            int i4 = csr[off + e + 4], i5 = csr[off + e + 5];
            int i6 = csr[off + e + 6], i7 = csr[off + e + 7];
            ushort4 v0 = *(const ushort4*)(es + (size_t)i0 * 32 + c4);
            ushort4 v1 = *(const ushort4*)(es + (size_t)i1 * 32 + c4);
            ushort4 v2 = *(const ushort4*)(es + (size_t)i2 * 32 + c4);
            ushort4 v3 = *(const ushort4*)(es + (size_t)i3 * 32 + c4);
            ushort4 v4 = *(const ushort4*)(es + (size_t)i4 * 32 + c4);
            ushort4 v5 = *(const ushort4*)(es + (size_t)i5 * 32 + c4);
            ushort4 v6 = *(const ushort4*)(es + (size_t)i6 * 32 + c4);
            ushort4 v7 = *(const ushort4*)(es + (size_t)i7 * 32 + c4);
            s0 += bf2f(v0.x) + bf2f(v2.x) + bf2f(v4.x) + bf2f(v6.x);
            t0 += bf2f(v1.x) + bf2f(v3.x) + bf2f(v5.x) + bf2f(v7.x);
            s1 += bf2f(v0.y) + bf2f(v2.y) + bf2f(v4.y) + bf2f(v6.y);
            t1 += bf2f(v1.y) + bf2f(v3.y) + bf2f(v5.y) + bf2f(v7.y);
            s2 += bf2f(v0.z) + bf2f(v2.z) + bf2f(v4.z) + bf2f(v6.z);
            t2 += bf2f(v1.z) + bf2f(v3.z) + bf2f(v5.z) + bf2f(v7.z);
            s3 += bf2f(v0.w) + bf2f(v2.w) + bf2f(v4.w) + bf2f(v6.w);
            t3 += bf2f(v1.w) + bf2f(v3.w) + bf2f(v5.w) + bf2f(v7.w);
        }
        for (; e < cnt; e++){
            ushort4 v = *(const ushort4*)(es + (size_t)csr[off + e] * 32 + c4);
            s0 += bf2f(v.x); s1 += bf2f(v.y); s2 += bf2f(v.z); s3 += bf2f(v.w);
        }
        float dv = dinv[node];
        float4 r;
        r.x = dv * (s0 + t0); r.y = dv * (s1 + t1);
        r.z = dv * (s2 + t2); r.w = dv * (s3 + t3);
        *(float4*)&a1t[g * 32 + c4] = r;
    }
    __syncthreads();
    // --- phase B: hs[rows] = bf16(dinv * relu(a1t @ W1 + b1)) ; 4 nodes x 4 cols ---
    int c4 = (threadIdx.x & 31) * 4;
    int r0 = (threadIdx.x >> 5) * 4;
    float4 bias = *(const float4*)(b1 + c4);
    float4 acc0 = bias, acc1 = bias, acc2 = bias, acc3 = bias;
    for (int k = 0; k < 32; k += 4){
        float4 a0  = *(const float4*)&a1t[(r0 + 0) * 32 + k];
        float4 a1v = *(const float4*)&a1t[(r0 + 1) * 32 + k];
        float4 a2v = *(const float4*)&a1t[(r0 + 2) * 32 + k];
        float4 a3v = *(const float4*)&a1t[(r0 + 3) * 32 + k];
        #pragma unroll
        for (int kk = 0; kk < 4; kk++){
            float4 wv = *(const float4*)&w[(k + kk) * 128 + c4];
            float b0 = (kk == 0) ? a0.x  : (kk == 1) ? a0.y  : (kk == 2) ? a0.z  : a0.w;
            float b1v= (kk == 0) ? a1v.x : (kk == 1) ? a1v.y : (kk == 2) ? a1v.z : a1v.w;
            float b2v= (kk == 0) ? a2v.x : (kk == 1) ? a2v.y : (kk == 2) ? a2v.z : a2v.w;
            float b3 = (kk == 0) ? a3v.x : (kk == 1) ? a3v.y : (kk == 2) ? a3v.z : a3v.w;
            acc0.x += b0 * wv.x; acc0.y += b0 * wv.y; acc0.z += b0 * wv.z; acc0.w += b0 * wv.w;
            acc1.x += b1v * wv.x; acc1.y += b1v * wv.y; acc1.z += b1v * wv.z; acc1.w += b1v * wv.w;
            acc2.x += b2v * wv.x; acc2.y += b2v * wv.y; acc2.z += b2v * wv.z; acc2.w += b2v * wv.w;
            acc3.x += b3 * wv.x; acc3.y += b3 * wv.y; acc3.z += b3 * wv.z; acc3.w += b3 * wv.w;
        }
    }
    int rb = blockIdx.x * 32 + r0;
    #pragma unroll
    for (int j = 0; j < 4; j++){
        int node2 = rb + j;
        if (node2 < n){
            float4 a = (j == 0) ? acc0 : (j == 1) ? acc1 : (j == 2) ? acc2 : acc3;
            float dv = dinv[node2];
            ushort4 o;
            o.x = f2bf(dv * fmaxf(a.x, 0.f));
            o.y = f2bf(dv * fmaxf(a.y, 0.f));
            o.z = f2bf(dv * fmaxf(a.z, 0.f));
            o.w = f2bf(dv * fmaxf(a.w, 0.f));
            *(ushort4*)(hs + (size_t)node2 * 128 + c4) = o;
        }
    }
}

// Layer 2 fused: gather(128-dim hs) -> LDS a2 tile (16 KB) -> GEMM W2 -> out.
// 32 nodes/block; phase A: 16 lanes/node x uint4 (16 B = 8 bf16), unroll 8;
// phase B: thread = 4 rows x 4 cols, W2 from global (64 KB, L1/L2-resident).
#define ACC8(dst, v) { dst[0] += bflo(v.x); dst[1] += bfhi(v.x);  \
                       dst[2] += bflo(v.y); dst[3] += bfhi(v.y);  \
                       dst[4] += bflo(v.z); dst[5] += bfhi(v.z);  \
                       dst[6] += bflo(v.w); dst[7] += bfhi(v.w); }

__global__ __launch_bounds__(256) void k_l2(const unsigned short* __restrict__ hs,
        const int* __restrict__ offsets, const int* __restrict__ ecount,
        const int* __restrict__ csr, const float* __restrict__ dinv,
        const float* __restrict__ W2, const float* __restrict__ b2,
        float* __restrict__ out, int n){
    __shared__ float a2t[32 * 128];   // 16 KB
    int g    = threadIdx.x >> 4;      // 16 groups
    int lane = threadIdx.x & 15;      // 16 lanes/node
    int c8   = lane * 8;
    // --- phase A: aggregate 2 nodes per group ---
    #pragma unroll
    for (int j = 0; j < 2; j++){
        int nl = g + 16 * j;
        int node = blockIdx.x * 32 + nl;
        if (node < n){
            int off = offsets[node], cnt = ecount[node];
            uint4 sv = *(const uint4*)(hs + (size_t)node * 128 + c8);   // self-loop
            float s[8] = {bflo(sv.x), bfhi(sv.x), bflo(sv.y), bfhi(sv.y),
                          bflo(sv.z), bfhi(sv.z), bflo(sv.w), bfhi(sv.w)};
            float t[8] = {0.f, 0.f, 0.f, 0.f, 0.f, 0.f, 0.f, 0.f};
            int e = 0;
            for (; e + 8 <= cnt; e += 8){
                int i0 = csr[off + e + 0], i1 = csr[off + e + 1];
                int i2 = csr[off + e + 2], i3 = csr[off + e + 3];
                int i4 = csr[off + e + 4], i5 = csr[off + e + 5];
                int i6 = csr[off + e + 6], i7 = csr[off + e + 7];
                uint4 v0 = *(const uint4*)(hs + (size_t)i0 * 128 + c8);
                uint4 v1 = *(const uint4*)(hs + (size_t)i1 * 128 + c8);
                uint4 v2 = *(const uint4*)(hs + (size_t)i2 * 128 + c8);
                uint4 v3 = *(const uint4*)(hs + (size_t)i3 * 128 + c8);
                uint4 v4 = *(const uint4*)(hs + (size_t)i4 * 128 + c8);
                uint4 v5 = *(const uint4*)(hs + (size_t)i5 * 128 + c8);
                uint4 v6 = *(const uint4*)(hs + (size_t)i6 * 128 + c8);
                uint4 v7 = *(const uint4*)(hs + (size_t)i7 * 128 + c8);
                ACC8(s, v0); ACC8(t, v1); ACC8(s, v2); ACC8(t, v3);
                ACC8(s, v4); ACC8(t, v5); ACC8(s, v6); ACC8(t, v7);
            }
            for (; e < cnt; e++){
                uint4 v = *(const uint4*)(hs + (size_t)csr[off + e] * 128 + c8);
                ACC8(s, v);
            }
            float dv = dinv[node];
            float4 r1, r2;
            r1.x = dv * (s[0] + t[0]); r1.y = dv * (s[1] + t[1]);
            r1.z = dv * (s[2] + t[2]); r1.w = dv * (s[3] + t[3]);
            r2.x = dv * (s[4] + t[4]); r2.y = dv * (s[5] + t[5]);
            r2.z = dv * (s[6] + t[6]); r2.w = dv * (s[7] + t[7]);
            *(float4*)&a2t[nl * 128 + c8]     = r1;
            *(float4*)&a2t[nl * 128 + c8 + 4] = r2;
        }
    }
    __syncthreads();
    // --- phase B: out[rows] = a2t[rows] @ W2 + b2 ; 4 rows x 4 cols/thread ---
    int c4 = (threadIdx.x & 31) * 4;
    int r0 = (threadIdx.x >> 5) * 4;
    float4 bias = *(const float4*)(b2 + c4);
    float4 acc0 = bias, acc1 = bias, acc2 = bias, acc3 = bias;
    for (int k = 0; k < 128; k += 4){
        float4 a0  = *(const float4*)&a2t[(r0 + 0) * 128 + k];
        float4 a1v = *(const float4*)&a2t[(r0 + 1) * 128 + k];
        float4 a2v = *(const float4*)&a2t[(r0 + 2) * 128 + k];
        float4 a3v = *(const float4*)&a2t[(r0 + 3) * 128 + k];
        #pragma unroll
        for (int kk = 0; kk < 4; kk++){
            float4 wv = *(const float4*)(W2 + (size_t)(k + kk) * 128 + c4);
            float b0 = (kk == 0) ? a0.x  : (kk == 1) ? a0.y  : (kk == 2) ? a0.z  : a0.w;
            float b1v= (kk == 0) ? a1v.x : (kk == 1) ? a1v.y : (kk == 2) ? a1v.z : a1v.w;
            float b2v= (kk == 0) ? a2v.x : (kk == 1) ? a2v.y : (kk == 2) ? a2v.z : a2v.w;
            float b3 = (kk == 0) ? a3v.x : (kk == 1) ? a3v.y : (kk == 2) ? a3v.z : a3v.w;
            acc0.x += b0 * wv.x; acc0.y += b0 * wv.y; acc0.z += b0 * wv.z; acc0.w += b0 * wv.w;
            acc1.x += b1v * wv.x; acc1.y += b1v * wv.y; acc1.z += b1v * wv.z; acc1.w += b1v * wv.w;
            acc2.x += b2v * wv.x; acc2.y += b2v * wv.y; acc2.z += b2v * wv.z; acc2.w += b2v * wv.w;
            acc3.x += b3 * wv.x; acc3.y += b3 * wv.y; acc3.z += b3 * wv.z; acc3.w += b3 * wv.w;
        }
    }
    int rb = blockIdx.x * 32 + r0;
    if (rb + 0 < n) *(float4*)(out + (size_t)(rb + 0) * 128 + c4) = acc0;
    if (rb + 1 < n) *(float4*)(out + (size_t)(rb + 1) * 128 + c4) = acc1;
    if (rb + 2 < n) *(float4*)(out + (size_t)(rb + 2) * 128 + c4) = acc2;
    if (rb + 3 < n) *(float4*)(out + (size_t)(rb + 3) * 128 + c4) = acc3;
}

extern "C" void kernel_launch(void* const* d_in, const int* in_sizes, int n_in,
                              void* d_out, int out_size, void* d_ws, size_t ws_size,
                              hipStream_t stream){
    const int*   x    = (const int*)d_in[0];
    const int*   ei   = (const int*)d_in[1];
    const float* emb  = (const float*)d_in[2];
    const float* W1   = (const float*)d_in[3];
    const float* b1   = (const float*)d_in[4];
    const float* W2   = (const float*)d_in[5];
    const float* b2   = (const float*)d_in[6];
    const int N = in_sizes[0];
    const int E = in_sizes[1] / 2;
    const int* srcv = ei;
    const int* dstv = ei + E;
    float* out = (float*)d_out;

    char* p = (char*)d_ws;
    auto alloc = [&](size_t bytes) -> char* {
        char* r = p; p += (bytes + 255) & ~(size_t)255; return r;
    };
    int nb = cdiv(N, 256);
    int*            ecount  = (int*)           alloc((size_t)(N + 8) * 4); // +8: gcur
    int*            gcur    = ecount + N;
    int*            offsets = (int*)           alloc((size_t)N * 4);
    int*            bsum    = (int*)           alloc((size_t)nb * 4);
    float*          dinv    = (float*)         alloc((size_t)N * 4);
    int*            csr     = (int*)           alloc((size_t)E * 4);
    unsigned short* es      = (unsigned short*)alloc((size_t)N * 32 * 2);
    int*            H       = (int*)           alloc((size_t)8 * NC * NPP * 4); // 6.4 MB
    unsigned short* hs      = (unsigned short*)alloc((size_t)N * 128 * 2);
    int*            staged  = (int*)           alloc((size_t)(E + 8 * 65536) * 4);
    (void)ws_size; (void)n_in; (void)out_size;

    const int npp = cdiv(N, 8);          // nodes per partition (== NPP for N=50000)
    const int C   = E / 8 + 65536;       // staged capacity per partition
    const int CH  = cdiv(C, NC);         // edges per chunk

    // --- CSR build (no global atomics on hot path) ---
    k_zero_i32<<<1, 64, 0, stream>>>(gcur, 8);
    k_bucket  <<<cdiv(E, 1024), 256, 0, stream>>>(srcv, dstv, E, staged, gcur, npp, C);
    k_hist    <<<8 * NC, 256, 0, stream>>>(staged, gcur, C, CH, npp, H);
    k_nodescan<<<nb, 256, 0, stream>>>(H, npp, N, ecount, dinv, bsum);
    k_scanBC  <<<nb, 256, 0, stream>>>(ecount, N, bsum, nb, offsets);
    k_fill3   <<<8 * NC, 256, 0, stream>>>(staged, gcur, C, CH, npp, H, offsets, csr);

    // --- layer 1 (fused): scale -> [gather+GEMM] -> hs ---
    k_scale <<<cdiv(N * 32, 256), 256, 0, stream>>>(emb, x, dinv, es, N);
    k_l1    <<<cdiv(N, 32), 256, 0, stream>>>(es, offsets, ecount, csr, dinv, W1, b1, hs, N);

    // --- layer 2 (fused): [gather+GEMM] -> out ---
    k_l2    <<<cdiv(N, 32), 256, 0, stream>>>(hs, offsets, ecount, csr, dinv, W2, b2, out, N);
}

// Round 12
// 268.126 us; speedup vs baseline: 1.1013x; 1.1013x over previous
//
#include <hip/hip_runtime.h>

// GCN: agg-before-GEMM on both layers (A(hW) = (Ah)W).
//   es  = bf16( dinv[i] * emb[x[i]] )               (N x 32, 3.2 MB, L2-resident)
//   L1 fused: a1(LDS) = dinv*(es[i]+sum es[src]);  hs = bf16(dinv*relu(a1@W1+b1))
//   L2 fused: a2(LDS) = dinv*(hs[i]+sum hs[src]);  out = a2@W2 + b2
// CSR build: bucket -> chunked-LDS-histogram counting sort (no global atomics),
// staged edges packed to one int ((dlocal<<17)|src) - halves staging traffic.
// R11 post-mortem: 8-lane k_l1 gather REGRESSED (wave spans 8 nodes -> edge-loop
// runs max-degree-of-8 vs max-of-2; divergence swamped inst savings); 16-lane
// k_l2 added 4-way LDS write conflicts + VGPR 48. Reverted both to R10 form
// (32 lanes/node) - measured best. Only the packed CSR staging is kept.

#define NPP   6250     // nodes per partition (N=50000 / 8)
#define NC    32       // chunks per partition

static inline int cdiv(int a, int b){ return (a + b - 1) / b; }

__device__ __forceinline__ unsigned short f2bf(float f){
    unsigned int u = __float_as_uint(f);
    u += 0x7fffu + ((u >> 16) & 1u);          // round-to-nearest-even
    return (unsigned short)(u >> 16);
}
__device__ __forceinline__ float bf2f(unsigned short b){
    return __uint_as_float(((unsigned int)b) << 16);
}

__global__ void k_zero_i32(int* __restrict__ p, int n){
    int i = blockIdx.x * blockDim.x + threadIdx.x;
    if (i < n) p[i] = 0;
}

// Bucket edges by dst-range into 8 staged partition arrays, packed
// (dlocal<<17)|src. LDS tiles, per-block coalesced flush (~2k gcur atomics total).
__global__ __launch_bounds__(256) void k_bucket(const int* __restrict__ src,
        const int* __restrict__ dst, int E, int* __restrict__ staged,
        int* __restrict__ gcur, int npp, int C){
    __shared__ int qcnt[8];
    __shared__ int qbase[8];
    __shared__ int qbuf[8 * 256];   // 8 KB
    int tid = threadIdx.x;
    if (tid < 8) qcnt[tid] = 0;
    __syncthreads();
    int e0 = blockIdx.x * 1024 + tid * 4;
    if (e0 + 3 < E){
        int4 d4 = *(const int4*)(dst + e0);
        int4 s4 = *(const int4*)(src + e0);
        int dd[4] = {d4.x, d4.y, d4.z, d4.w};
        int ss[4] = {s4.x, s4.y, s4.z, s4.w};
        #pragma unroll
        for (int i = 0; i < 4; i++){
            int p = dd[i] / npp;
            int pk = ((dd[i] - p * npp) << 17) | ss[i];
            int pos = atomicAdd(&qcnt[p], 1);
            if (pos < 256) qbuf[p * 256 + pos] = pk;
            else {          // statistically unreachable overflow fallback
                int gp = atomicAdd(&gcur[p], 1);
                staged[(size_t)p * C + gp] = pk;
            }
        }
    } else {
        for (int e = e0; e < E && e < e0 + 4; e++){
            int d = dst[e], s = src[e];
            int p = d / npp;
            int pk = ((d - p * npp) << 17) | s;
            int pos = atomicAdd(&qcnt[p], 1);
            if (pos < 256) qbuf[p * 256 + pos] = pk;
            else {
                int gp = atomicAdd(&gcur[p], 1);
                staged[(size_t)p * C + gp] = pk;
            }
        }
    }
    __syncthreads();
    if (tid < 8){
        int nq = min(qcnt[tid], 256);
        qbase[tid] = (nq > 0) ? atomicAdd(&gcur[tid], nq) : 0;
    }
    __syncthreads();
    for (int b = 0; b < 8; b++){
        int nq = min(qcnt[b], 256);
        int gb = qbase[b];
        for (int i = tid; i < nq; i += 256)
            staged[(size_t)b * C + gb + i] = qbuf[b * 256 + i];
    }
}

// Per-(partition,chunk) dst histogram via LDS atomics -> H[p][c][0..npp).
__global__ __launch_bounds__(256) void k_hist(const int* __restrict__ staged,
        const int* __restrict__ gcur, int C, int CH, int npp, int* __restrict__ H){
    __shared__ int hist[NPP];
    int part  = blockIdx.x & 7;
    int chunk = blockIdx.x >> 3;
    int tid = threadIdx.x;
    for (int i = tid; i < npp; i += 256) hist[i] = 0;
    __syncthreads();
    int pc = gcur[part];
    int e0 = chunk * CH, e1 = min(e0 + CH, pc);
    const int* sd = staged + (size_t)part * C;
    for (int e = e0 + tid; e < e1; e += 256)
        atomicAdd(&hist[(unsigned)sd[e] >> 17], 1);
    __syncthreads();
    int* Hrow = H + (size_t)(part * NC + chunk) * npp;
    for (int i = tid; i < npp; i += 256) Hrow[i] = hist[i];
}

// Per-node serial prefix over the NC chunk histograms: H becomes per-chunk
// exclusive base rank; ecount = total; dinv fused; per-block sums -> bsum.
__global__ __launch_bounds__(256) void k_nodescan(int* __restrict__ H, int npp, int n,
        int* __restrict__ ecount, float* __restrict__ dinv, int* __restrict__ bsum){
    __shared__ int s[256];
    int t = blockIdx.x * 256 + threadIdx.x;   // t == node id (partitions contiguous)
    int run = 0;
    if (t < 8 * npp && t < n){
        int p  = t / npp;
        int dl = t - p * npp;
        #pragma unroll
        for (int c = 0; c < NC; c++){
            size_t idx = (size_t)(p * NC + c) * npp + dl;
            int v = H[idx];
            H[idx] = run;
            run += v;
        }
        ecount[t] = run;
        dinv[t] = rsqrtf((float)run + 1.0f);   // +1 self-loop
    }
    s[threadIdx.x] = run;
    __syncthreads();
    for (int d = 128; d > 0; d >>= 1){
        if (threadIdx.x < d) s[threadIdx.x] += s[threadIdx.x + d];
        __syncthreads();
    }
    if (threadIdx.x == 0) bsum[blockIdx.x] = s[0];
}

// Fused scanB+scanC: every block re-scans the nb block sums in LDS (nb<=256),
// then does its 256-element Hillis-Steele scan -> offsets.
__global__ __launch_bounds__(256) void k_scanBC(const int* __restrict__ ecount, int n,
        const int* __restrict__ bsum, int nb, int* __restrict__ offsets){
    __shared__ int bs[256];
    __shared__ int s[256];
    int t = threadIdx.x;
    bs[t] = (t < nb) ? bsum[t] : 0;
    __syncthreads();
    if (t == 0){
        int run = 0;
        for (int b = 0; b < nb; b++){ int v = bs[b]; bs[b] = run; run += v; }
    }
    __syncthreads();
    int i = blockIdx.x * 256 + t;
    int v = (i < n) ? ecount[i] : 0;
    s[t] = v;
    __syncthreads();
    for (int d = 1; d < 256; d <<= 1){
        int x = (t >= d) ? s[t - d] : 0;
        __syncthreads();
        s[t] += x;
        __syncthreads();
    }
    if (i < n) offsets[i] = bs[blockIdx.x] + s[t] - v;
}

// Fill csr via LDS cursor preloaded with chunk base ranks. No global atomics.
__global__ __launch_bounds__(256) void k_fill3(const int* __restrict__ staged,
        const int* __restrict__ gcur, int C, int CH, int npp,
        const int* __restrict__ H, const int* __restrict__ offsets,
        int* __restrict__ csr_src){
    __shared__ int cur[NPP];
    int part  = blockIdx.x & 7;
    int chunk = blockIdx.x >> 3;
    int tid = threadIdx.x;
    const int* Hrow = H + (size_t)(part * NC + chunk) * npp;
    for (int i = tid; i < npp; i += 256) cur[i] = Hrow[i];
    __syncthreads();
    int pc = gcur[part];
    int lo = part * npp;
    int e0 = chunk * CH, e1 = min(e0 + CH, pc);
    const int* sd = staged + (size_t)part * C;
    for (int e = e0 + tid; e < e1; e += 256){
        int pk = sd[e];
        int dl = (unsigned)pk >> 17;
        int r = atomicAdd(&cur[dl], 1);
        csr_src[offsets[lo + dl] + r] = pk & 0x1FFFF;
    }
}

// es[i][c] = bf16( emb[x[i]][c] * dinv[i] )
__global__ void k_scale(const float* __restrict__ emb, const int* __restrict__ x,
                        const float* __restrict__ dinv, unsigned short* __restrict__ es, int n){
    int idx = blockIdx.x * blockDim.x + threadIdx.x;
    if (idx >= n * 32) return;
    int i = idx >> 5;
    int c = idx & 31;
    es[idx] = f2bf(emb[(size_t)x[i] * 32 + c] * dinv[i]);
}

// Layer 1 fused (R10 form): gather(32-dim es) -> LDS a1 tile -> GEMM W1 -> hs.
// 8 nodes/block; phase A: 32 lanes/node (wave = 2 nodes, min divergence),
// bf16 scalar loads, unroll 8; phase B: 128 cols vs W1 in LDS.
__global__ __launch_bounds__(256) void k_l1(const unsigned short* __restrict__ es,
        const int* __restrict__ offsets, const int* __restrict__ ecount,
        const int* __restrict__ csr, const float* __restrict__ dinv,
        const float* __restrict__ W1, const float* __restrict__ b1,
        unsigned short* __restrict__ hs, int n){
    __shared__ float w[32 * 128];     // 16 KB
    __shared__ float a1t[8][32];      // 1 KB
    for (int i = threadIdx.x; i < 32 * 128; i += 256) w[i] = W1[i];
    int g    = threadIdx.x >> 5;
    int lane = threadIdx.x & 31;
    int node = blockIdx.x * 8 + g;
    // --- phase A: aggregate into LDS ---
    if (node < n){
        int off = offsets[node], cnt = ecount[node];
        float s0 = bf2f(es[(size_t)node * 32 + lane]);   // self-loop term
        float s1 = 0.f;
        int e = 0;
        for (; e + 8 <= cnt; e += 8){
            int i0 = csr[off + e + 0], i1 = csr[off + e + 1];
            int i2 = csr[off + e + 2], i3 = csr[off + e + 3];
            int i4 = csr[off + e + 4], i5 = csr[off + e + 5];
            int i6 = csr[off + e + 6], i7 = csr[off + e + 7];
            unsigned short v0 = es[(size_t)i0 * 32 + lane];
            unsigned short v1 = es[(size_t)i1 * 32 + lane];
            unsigned short v2 = es[(size_t)i2 * 32 + lane];
            unsigned short v3 = es[(size_t)i3 * 32 + lane];
            unsigned short v4 = es[(size_t)i4 * 32 + lane];
            unsigned short v5 = es[(size_t)i5 * 32 + lane];
            unsigned short v6 = es[(size_t)i6 * 32 + lane];
            unsigned short v7 = es[(size_t)i7 * 32 + lane];
            s0 += bf2f(v0) + bf2f(v2) + bf2f(v4) + bf2f(v6);
            s1 += bf2f(v1) + bf2f(v3) + bf2f(v5) + bf2f(v7);
        }
        for (; e < cnt; e++) s0 += bf2f(es[(size_t)csr[off + e] * 32 + lane]);
        a1t[g][lane] = dinv[node] * (s0 + s1);
    }
    __syncthreads();
    // --- phase B: hs[node] = bf16(dinv * relu(a1 @ W1 + b1)) ---
    if (node >= n) return;
    int c4 = lane * 4;
    float4 acc = *(const float4*)(b1 + c4);
    #pragma unroll
    for (int k4 = 0; k4 < 8; k4++){
        float4 av = *(const float4*)&a1t[g][k4 * 4];
        float4 w0 = *(const float4*)&w[(k4 * 4 + 0) * 128 + c4];
        float4 w1 = *(const float4*)&w[(k4 * 4 + 1) * 128 + c4];
        float4 w2 = *(const float4*)&w[(k4 * 4 + 2) * 128 + c4];
        float4 w3 = *(const float4*)&w[(k4 * 4 + 3) * 128 + c4];
        acc.x += av.x * w0.x + av.y * w1.x + av.z * w2.x + av.w * w3.x;
        acc.y += av.x * w0.y + av.y * w1.y + av.z * w2.y + av.w * w3.y;
        acc.z += av.x * w0.z + av.y * w1.z + av.z * w2.z + av.w * w3.z;
        acc.w += av.x * w0.w + av.y * w1.w + av.z * w2.w + av.w * w3.w;
    }
    float dv = dinv[node];
    ushort4 o;
    o.x = f2bf(dv * fmaxf(acc.x, 0.f));
    o.y = f2bf(dv * fmaxf(acc.y, 0.f));
    o.z = f2bf(dv * fmaxf(acc.z, 0.f));
    o.w = f2bf(dv * fmaxf(acc.w, 0.f));
    *(ushort4*)(hs + (size_t)node * 128 + c4) = o;
}

// Layer 2 fused (R10 form): gather(128-dim hs) -> LDS a2 tile (16 KB) -> GEMM W2.
// 32 nodes/block; phase A: 8 groups x 32 lanes, 4 nodes/group, ushort4, unroll 8;
// phase B: thread = 4 rows x 4 cols, W2 from global (64 KB, L1/L2-resident).
__global__ __launch_bounds__(256) void k_l2(const unsigned short* __restrict__ hs,
        const int* __restrict__ offsets, const int* __restrict__ ecount,
        const int* __restrict__ csr, const float* __restrict__ dinv,
        const float* __restrict__ W2, const float* __restrict__ b2,
        float* __restrict__ out, int n){
    __shared__ float a2t[32 * 128];   // 16 KB
    int g    = threadIdx.x >> 5;
    int lane = threadIdx.x & 31;
    int c4g  = lane * 4;
    // --- phase A: aggregate 4 nodes per 32-lane group ---
    #pragma unroll
    for (int j = 0; j < 4; j++){
        int nl = g + 8 * j;
        int node = blockIdx.x * 32 + nl;
        if (node < n){
            int off = offsets[node], cnt = ecount[node];
            ushort4 sv = *(const ushort4*)(hs + (size_t)node * 128 + c4g);
            float ax0 = bf2f(sv.x), ax1 = 0.f;
            float ay0 = bf2f(sv.y), ay1 = 0.f;
            float az0 = bf2f(sv.z), az1 = 0.f;
            float aw0 = bf2f(sv.w), aw1 = 0.f;
            int e = 0;
            for (; e + 8 <= cnt; e += 8){
                int i0 = csr[off + e + 0], i1 = csr[off + e + 1];
                int i2 = csr[off + e + 2], i3 = csr[off + e + 3];
                int i4 = csr[off + e + 4], i5 = csr[off + e + 5];
                int i6 = csr[off + e + 6], i7 = csr[off + e + 7];
                ushort4 v0 = *(const ushort4*)(hs + (size_t)i0 * 128 + c4g);
                ushort4 v1 = *(const ushort4*)(hs + (size_t)i1 * 128 + c4g);
                ushort4 v2 = *(const ushort4*)(hs + (size_t)i2 * 128 + c4g);
                ushort4 v3 = *(const ushort4*)(hs + (size_t)i3 * 128 + c4g);
                ushort4 v4 = *(const ushort4*)(hs + (size_t)i4 * 128 + c4g);
                ushort4 v5 = *(const ushort4*)(hs + (size_t)i5 * 128 + c4g);
                ushort4 v6 = *(const ushort4*)(hs + (size_t)i6 * 128 + c4g);
                ushort4 v7 = *(const ushort4*)(hs + (size_t)i7 * 128 + c4g);
                ax0 += bf2f(v0.x) + bf2f(v2.x) + bf2f(v4.x) + bf2f(v6.x);
                ax1 += bf2f(v1.x) + bf2f(v3.x) + bf2f(v5.x) + bf2f(v7.x);
                ay0 += bf2f(v0.y) + bf2f(v2.y) + bf2f(v4.y) + bf2f(v6.y);
                ay1 += bf2f(v1.y) + bf2f(v3.y) + bf2f(v5.y) + bf2f(v7.y);
                az0 += bf2f(v0.z) + bf2f(v2.z) + bf2f(v4.z) + bf2f(v6.z);
                az1 += bf2f(v1.z) + bf2f(v3.z) + bf2f(v5.z) + bf2f(v7.z);
                aw0 += bf2f(v0.w) + bf2f(v2.w) + bf2f(v4.w) + bf2f(v6.w);
                aw1 += bf2f(v1.w) + bf2f(v3.w) + bf2f(v5.w) + bf2f(v7.w);
            }
            for (; e < cnt; e++){
                ushort4 v = *(const ushort4*)(hs + (size_t)csr[off + e] * 128 + c4g);
                ax0 += bf2f(v.x); ay0 += bf2f(v.y); az0 += bf2f(v.z); aw0 += bf2f(v.w);
            }
            float dv = dinv[node];
            float4 r;
            r.x = dv * (ax0 + ax1); r.y = dv * (ay0 + ay1);
            r.z = dv * (az0 + az1); r.w = dv * (aw0 + aw1);
            *(float4*)&a2t[nl * 128 + c4g] = r;
        }
    }
    __syncthreads();
    // --- phase B: out[rows] = a2t[rows] @ W2 + b2 ; 4 rows x 4 cols/thread ---
    int c4 = lane * 4;                 // output col base
    int r0 = (threadIdx.x >> 5) * 4;   // 4 local rows
    float4 bias = *(const float4*)(b2 + c4);
    float4 acc0 = bias, acc1 = bias, acc2 = bias, acc3 = bias;
    for (int k = 0; k < 128; k += 4){
        float4 a0  = *(const float4*)&a2t[(r0 + 0) * 128 + k];
        float4 a1v = *(const float4*)&a2t[(r0 + 1) * 128 + k];
        float4 a2v = *(const float4*)&a2t[(r0 + 2) * 128 + k];
        float4 a3v = *(const float4*)&a2t[(r0 + 3) * 128 + k];
        #pragma unroll
        for (int kk = 0; kk < 4; kk++){
            float4 wv = *(const float4*)(W2 + (size_t)(k + kk) * 128 + c4);
            float b0 = (kk == 0) ? a0.x  : (kk == 1) ? a0.y  : (kk == 2) ? a0.z  : a0.w;
            float b1v= (kk == 0) ? a1v.x : (kk == 1) ? a1v.y : (kk == 2) ? a1v.z : a1v.w;
            float b2v= (kk == 0) ? a2v.x : (kk == 1) ? a2v.y : (kk == 2) ? a2v.z : a2v.w;
            float b3 = (kk == 0) ? a3v.x : (kk == 1) ? a3v.y : (kk == 2) ? a3v.z : a3v.w;
            acc0.x += b0 * wv.x; acc0.y += b0 * wv.y; acc0.z += b0 * wv.z; acc0.w += b0 * wv.w;
            acc1.x += b1v * wv.x; acc1.y += b1v * wv.y; acc1.z += b1v * wv.z; acc1.w += b1v * wv.w;
            acc2.x += b2v * wv.x; acc2.y += b2v * wv.y; acc2.z += b2v * wv.z; acc2.w += b2v * wv.w;
            acc3.x += b3 * wv.x; acc3.y += b3 * wv.y; acc3.z += b3 * wv.z; acc3.w += b3 * wv.w;
        }
    }
    int rb = blockIdx.x * 32 + r0;
    if (rb + 0 < n) *(float4*)(out + (size_t)(rb + 0) * 128 + c4) = acc0;
    if (rb + 1 < n) *(float4*)(out + (size_t)(rb + 1) * 128 + c4) = acc1;
    if (rb + 2 < n) *(float4*)(out + (size_t)(rb + 2) * 128 + c4) = acc2;
    if (rb + 3 < n) *(float4*)(out + (size_t)(rb + 3) * 128 + c4) = acc3;
}

extern "C" void kernel_launch(void* const* d_in, const int* in_sizes, int n_in,
                              void* d_out, int out_size, void* d_ws, size_t ws_size,
                              hipStream_t stream){
    const int*   x    = (const int*)d_in[0];
    const int*   ei   = (const int*)d_in[1];
    const float* emb  = (const float*)d_in[2];
    const float* W1   = (const float*)d_in[3];
    const float* b1   = (const float*)d_in[4];
    const float* W2   = (const float*)d_in[5];
    const float* b2   = (const float*)d_in[6];
    const int N = in_sizes[0];
    const int E = in_sizes[1] / 2;
    const int* srcv = ei;
    const int* dstv = ei + E;
    float* out = (float*)d_out;

    char* p = (char*)d_ws;
    auto alloc = [&](size_t bytes) -> char* {
        char* r = p; p += (bytes + 255) & ~(size_t)255; return r;
    };
    int nb = cdiv(N, 256);
    int*            ecount  = (int*)           alloc((size_t)(N + 8) * 4); // +8: gcur
    int*            gcur    = ecount + N;
    int*            offsets = (int*)           alloc((size_t)N * 4);
    int*            bsum    = (int*)           alloc((size_t)nb * 4);
    float*          dinv    = (float*)         alloc((size_t)N * 4);
    int*            csr     = (int*)           alloc((size_t)E * 4);
    unsigned short* es      = (unsigned short*)alloc((size_t)N * 32 * 2);
    int*            H       = (int*)           alloc((size_t)8 * NC * NPP * 4); // 6.4 MB
    unsigned short* hs      = (unsigned short*)alloc((size_t)N * 128 * 2);
    int*            staged  = (int*)           alloc((size_t)(E + 8 * 65536) * 4);
    (void)ws_size; (void)n_in; (void)out_size;

    const int npp = cdiv(N, 8);          // nodes per partition (== NPP for N=50000)
    const int C   = E / 8 + 65536;       // staged capacity per partition
    const int CH  = cdiv(C, NC);         // edges per chunk

    // --- CSR build (no global atomics on hot path) ---
    k_zero_i32<<<1, 64, 0, stream>>>(gcur, 8);
    k_bucket  <<<cdiv(E, 1024), 256, 0, stream>>>(srcv, dstv, E, staged, gcur, npp, C);
    k_hist    <<<8 * NC, 256, 0, stream>>>(staged, gcur, C, CH, npp, H);
    k_nodescan<<<nb, 256, 0, stream>>>(H, npp, N, ecount, dinv, bsum);
    k_scanBC  <<<nb, 256, 0, stream>>>(ecount, N, bsum, nb, offsets);
    k_fill3   <<<8 * NC, 256, 0, stream>>>(staged, gcur, C, CH, npp, H, offsets, csr);

    // --- layer 1 (fused): scale -> [gather+GEMM] -> hs ---
    k_scale <<<cdiv(N * 32, 256), 256, 0, stream>>>(emb, x, dinv, es, N);
    k_l1    <<<cdiv(N, 8), 256, 0, stream>>>(es, offsets, ecount, csr, dinv, W1, b1, hs, N);

    // --- layer 2 (fused): [gather+GEMM] -> out ---
    k_l2    <<<cdiv(N, 32), 256, 0, stream>>>(hs, offsets, ecount, csr, dinv, W2, b2, out, N);
}